// Round 12
// baseline (273.780 us; speedup 1.0000x reference)
//
#include <hip/hip_runtime.h>
#include <math.h>

#define D_MODEL 256
#define NHEAD 4
#define HEAD_DIM 64
#define SEQ 4096
#define BATCH 4
#define MROWS (BATCH * SEQ)

typedef __attribute__((ext_vector_type(8))) short short8;
typedef __attribute__((ext_vector_type(4))) short short4v;
typedef __attribute__((ext_vector_type(8))) __bf16 bf16x8;
typedef __attribute__((ext_vector_type(4))) float f32x4;

__device__ inline short f2bf(float f) {  // RNE fp32->bf16
  unsigned u = __float_as_uint(f);
  u += 0x7fffu + ((u >> 16) & 1u);
  return (short)(u >> 16);
}
__device__ inline bf16x8 as_bf8(short8 s) {
  union { short8 s; bf16x8 b; } u;
  u.s = s;
  return u.b;
}
// async global->LDS, 16B per lane; LDS dest = wave-uniform base + lane*16
__device__ __forceinline__ void g2lds16(const void* g, void* l) {
  __builtin_amdgcn_global_load_lds(
      (const __attribute__((address_space(1))) unsigned int*)g,
      (__attribute__((address_space(3))) unsigned int*)l, 16, 0, 0);
}

// 16x16x16 bf16 MFMA: B-operand k-map (quad*4+j) == QK C-layout k-map,
// so P feeds PV straight from registers (no LDS round-trip).
__device__ __forceinline__ f32x4 mfma16bf(short4v a, short4v b, f32x4 c) {
#if __has_builtin(__builtin_amdgcn_mfma_f32_16x16x16bf16_1k)
  return __builtin_amdgcn_mfma_f32_16x16x16bf16_1k(a, b, c, 0, 0, 0);
#else
  asm("v_mfma_f32_16x16x16_bf16 %0, %1, %2, %0" : "+v"(c) : "v"(a), "v"(b));
  return c;
#endif
}

#define QSCALE 0.1803368801111204f  /* 0.125 * log2(e): exp2-domain scores */

// ---- weight cvt fp32->bf16, row-major with XOR-swizzled 16B groups --------
// element (n,k) -> n*256 + (k>>5)*32 + (((k>>3)&3) ^ (n&3))*8 + (k&7)
__global__ __launch_bounds__(256) void wcvt(const float* __restrict__ s0, const float* __restrict__ s1,
                                            const float* __restrict__ s2, const float* __restrict__ s3,
                                            const float* __restrict__ s4, short* __restrict__ d0,
                                            short* __restrict__ d1, short* __restrict__ d2,
                                            short* __restrict__ d3, short* __restrict__ d4) {
  int mat = blockIdx.x >> 5;
  int e = ((blockIdx.x & 31) * 256 + threadIdx.x) * 8;
  const float* s = mat == 0 ? s0 : mat == 1 ? s1 : mat == 2 ? s2 : mat == 3 ? s3 : s4;
  short* d = mat == 0 ? d0 : mat == 1 ? d1 : mat == 2 ? d2 : mat == 3 ? d3 : d4;
  int n = e >> 8, k0 = e & 255;
  float4 f0 = *(const float4*)(s + n * 256 + k0);
  float4 f1 = *(const float4*)(s + n * 256 + k0 + 4);
  short8 o = {f2bf(f0.x), f2bf(f0.y), f2bf(f0.z), f2bf(f0.w),
              f2bf(f1.x), f2bf(f1.y), f2bf(f1.z), f2bf(f1.w)};
  int chunk = k0 >> 5, g = (k0 >> 3) & 3;
  *(short8*)(d + n * 256 + chunk * 32 + ((g ^ (n & 3)) * 8)) = o;
}

// ---- QKV GEMM with fused LayerNorm1 (verified R10, best-total config) -----
__global__ __launch_bounds__(256) void qkv_ln(
    const short* __restrict__ Wqi, const short* __restrict__ Wki,
    const short* __restrict__ Wvi, const float* __restrict__ x,
    const float* __restrict__ g1v, const float* __restrict__ b1v,
    short* __restrict__ qo, short* __restrict__ kimg, short* __restrict__ vimg) {
  __shared__ __align__(16) short Xs[64 * 256];  // 32 KB
  const int t = threadIdx.x, lane = t & 63, w = t >> 6;
  const int l15 = lane & 15, quad = lane >> 4;
  const int m0 = blockIdx.x * 64;
  const int which = blockIdx.y;
  const short* Wb = which == 0 ? Wqi : which == 1 ? Wki : Wvi;

  // ---- fused LN1: 8 rows per pass (32 thr/row), 8 passes -> Xs swizzled ----
  {
    const int r = t >> 5, c8 = t & 31;
    float4 ga = *(const float4*)(g1v + c8 * 8);
    float4 gc = *(const float4*)(g1v + c8 * 8 + 4);
    float4 ba = *(const float4*)(b1v + c8 * 8);
    float4 bc = *(const float4*)(b1v + c8 * 8 + 4);
#pragma unroll
    for (int pass = 0; pass < 8; pass++) {
      int row = pass * 8 + r;
      const float* xr = x + (size_t)(m0 + row) * D_MODEL + c8 * 8;
      float4 a = *(const float4*)xr;
      float4 c = *(const float4*)(xr + 4);
      float s = a.x + a.y + a.z + a.w + c.x + c.y + c.z + c.w;
#pragma unroll
      for (int off = 16; off > 0; off >>= 1) s += __shfl_xor(s, off);
      float mu = s * (1.0f / D_MODEL);
      float d0 = a.x - mu, d1 = a.y - mu, d2 = a.z - mu, d3 = a.w - mu;
      float d4 = c.x - mu, d5 = c.y - mu, d6 = c.z - mu, d7 = c.w - mu;
      float ss = d0 * d0 + d1 * d1 + d2 * d2 + d3 * d3 + d4 * d4 + d5 * d5 + d6 * d6 + d7 * d7;
#pragma unroll
      for (int off = 16; off > 0; off >>= 1) ss += __shfl_xor(ss, off);
      float rstd = rsqrtf(ss * (1.0f / D_MODEL) + 1e-5f);
      short8 ov = {f2bf(d0 * rstd * ga.x + ba.x), f2bf(d1 * rstd * ga.y + ba.y),
                   f2bf(d2 * rstd * ga.z + ba.z), f2bf(d3 * rstd * ga.w + ba.w),
                   f2bf(d4 * rstd * gc.x + bc.x), f2bf(d5 * rstd * gc.y + bc.y),
                   f2bf(d6 * rstd * gc.z + bc.z), f2bf(d7 * rstd * gc.w + bc.w)};
      int chunk = c8 >> 2, gr = c8 & 3;
      *(short8*)&Xs[row * 256 + chunk * 32 + ((gr ^ (row & 3)) * 8)] = ov;
    }
  }
  __syncthreads();

  // hoisted fragment bases (all further offsets compile-time)
  const short* xb = &Xs[l15 * 256 + ((quad ^ (l15 & 3)) * 8)];
  const short* wb = Wb + (size_t)(w * 64 + l15) * 256 + ((quad ^ (l15 & 3)) * 8);

  f32x4 acc[4][4];
#pragma unroll
  for (int i = 0; i < 4; i++)
#pragma unroll
    for (int j = 0; j < 4; j++) acc[i][j] = (f32x4){0.f, 0.f, 0.f, 0.f};

#pragma unroll
  for (int kf = 0; kf < 8; kf++) {
    bf16x8 fx[4], fw[4];
#pragma unroll
    for (int i = 0; i < 4; i++) {
      fx[i] = as_bf8(*(const short8*)(xb + i * 4096 + kf * 32));
      fw[i] = as_bf8(*(const short8*)(wb + i * 4096 + kf * 32));
    }
    if (which == 2) {
#pragma unroll
      for (int mt = 0; mt < 4; mt++)
#pragma unroll
        for (int nt = 0; nt < 4; nt++)
          acc[mt][nt] = __builtin_amdgcn_mfma_f32_16x16x32_bf16(fx[mt], fw[nt], acc[mt][nt], 0, 0, 0);
    } else {
#pragma unroll
      for (int mt = 0; mt < 4; mt++)
#pragma unroll
        for (int nt = 0; nt < 4; nt++)
          acc[mt][nt] = __builtin_amdgcn_mfma_f32_16x16x32_bf16(fw[nt], fx[mt], acc[mt][nt], 0, 0, 0);
    }
  }

#pragma unroll
  for (int mt = 0; mt < 4; mt++)
#pragma unroll
    for (int nt = 0; nt < 4; nt++) {
      f32x4 v = acc[mt][nt];
      if (which == 2) {  // VT image: C[m=s][n=feature] (rows via quad*4+r)
        int n = w * 64 + nt * 16 + l15;
        int mr = m0 + mt * 16 + quad * 4;
        int b = mr >> 12, s = mr & 4095, h = n >> 6, d = n & 63;
        size_t off = ((size_t)(b * NHEAD + h) * 64 + (s >> 6)) * 4096 +
                     (size_t)d * 64 + ((((s & 63) >> 3) ^ (d & 7)) * 8) + (s & 7);
        short4v o = {f2bf(v[0]), f2bf(v[1]), f2bf(v[2]), f2bf(v[3])};
        *(short4v*)(vimg + off) = o;
      } else {  // C[n][m]: col = m via l15, row = n via quad*4+r
        int m = m0 + mt * 16 + l15;
        int nb = w * 64 + nt * 16 + quad * 4;
        if (which == 0) {  // Q row-major, exp2-domain scale folded in
          v *= QSCALE;
          short4v o = {f2bf(v[0]), f2bf(v[1]), f2bf(v[2]), f2bf(v[3])};
          *(short4v*)(qo + (size_t)m * D_MODEL + nb) = o;
        } else {  // K image
          int b = m >> 12, s = m & 4095, h = nb >> 6, d = nb & 63;
          size_t off = ((size_t)(b * NHEAD + h) * 64 + (s >> 6)) * 4096 +
                       (size_t)(s & 63) * 64 + (((d >> 3) ^ (s & 7)) * 8) + (d & 7);
          short4v o = {f2bf(v[0]), f2bf(v[1]), f2bf(v[2]), f2bf(v[3])};
          *(short4v*)(kimg + off) = o;
        }
      }
    }
}

// ---- FFN with fused LayerNorm2 (verified R4-R11) --------------------------
__global__ __launch_bounds__(256) void ffn_ln(
    const short* __restrict__ w1i, const short* __restrict__ w2i,
    const float* __restrict__ g2v, const float* __restrict__ b2v,
    const float* __restrict__ bf1, const float* __restrict__ bf2,
    const float* __restrict__ xt, float* __restrict__ out) {
  __shared__ __align__(16) short Hs[32 * 256];   // 16 KB (image layout)
  __shared__ __align__(16) short F1s[32 * 264];  // 16.5 KB (padded rows)
  const int t = threadIdx.x, lane = t & 63, w = t >> 6;
  const int l15 = lane & 15, quad = lane >> 4;
  const int m0 = blockIdx.x * 32;

  // ---- fused LN2: 8 rows per pass (32 thr/row), 4 passes -> Hs swizzled ----
  {
    const int r = t >> 5, c8 = t & 31;
    float4 ga = *(const float4*)(g2v + c8 * 8);
    float4 gc = *(const float4*)(g2v + c8 * 8 + 4);
    float4 ba = *(const float4*)(b2v + c8 * 8);
    float4 bc = *(const float4*)(b2v + c8 * 8 + 4);
#pragma unroll
    for (int pass = 0; pass < 4; pass++) {
      int row = pass * 8 + r;
      const float* xr = xt + (size_t)(m0 + row) * D_MODEL + c8 * 8;
      float4 a = *(const float4*)xr;
      float4 c = *(const float4*)(xr + 4);
      float s = a.x + a.y + a.z + a.w + c.x + c.y + c.z + c.w;
#pragma unroll
      for (int off = 16; off > 0; off >>= 1) s += __shfl_xor(s, off);
      float mu = s * (1.0f / D_MODEL);
      float d0 = a.x - mu, d1 = a.y - mu, d2 = a.z - mu, d3 = a.w - mu;
      float d4 = c.x - mu, d5 = c.y - mu, d6 = c.z - mu, d7 = c.w - mu;
      float ss = d0 * d0 + d1 * d1 + d2 * d2 + d3 * d3 + d4 * d4 + d5 * d5 + d6 * d6 + d7 * d7;
#pragma unroll
      for (int off = 16; off > 0; off >>= 1) ss += __shfl_xor(ss, off);
      float rstd = rsqrtf(ss * (1.0f / D_MODEL) + 1e-5f);
      short8 ov = {f2bf(d0 * rstd * ga.x + ba.x), f2bf(d1 * rstd * ga.y + ba.y),
                   f2bf(d2 * rstd * ga.z + ba.z), f2bf(d3 * rstd * ga.w + ba.w),
                   f2bf(d4 * rstd * gc.x + bc.x), f2bf(d5 * rstd * gc.y + bc.y),
                   f2bf(d6 * rstd * gc.z + bc.z), f2bf(d7 * rstd * gc.w + bc.w)};
      int chunk = c8 >> 2, gr = c8 & 3;
      *(short8*)&Hs[row * 256 + chunk * 32 + ((gr ^ (row & 3)) * 8)] = ov;
    }
  }
  __syncthreads();

  const short* hb = &Hs[l15 * 256 + ((quad ^ (l15 & 3)) * 8)];
  const short* w1b = w1i + (size_t)(w * 64 + l15) * 256 + ((quad ^ (l15 & 3)) * 8);
  const short* w2b = w2i + (size_t)(w * 64 + l15) * 256 + ((quad ^ (l15 & 3)) * 8);

  // ---- GEMM1: C[n1][m] = W1 . h^T ; wave owns 64 n1, all 32 m ----
  f32x4 a1[2][4];
#pragma unroll
  for (int i = 0; i < 2; i++)
#pragma unroll
    for (int j = 0; j < 4; j++) a1[i][j] = (f32x4){0.f, 0.f, 0.f, 0.f};
#pragma unroll
  for (int kf = 0; kf < 8; kf++) {
    bf16x8 fh[2], fw1[4];
#pragma unroll
    for (int i = 0; i < 2; i++) fh[i] = as_bf8(*(const short8*)(hb + i * 4096 + kf * 32));
#pragma unroll
    for (int i = 0; i < 4; i++) fw1[i] = as_bf8(*(const short8*)(w1b + i * 4096 + kf * 32));
#pragma unroll
    for (int mt = 0; mt < 2; mt++)
#pragma unroll
      for (int nt = 0; nt < 4; nt++)
        a1[mt][nt] = __builtin_amdgcn_mfma_f32_16x16x32_bf16(fw1[nt], fh[mt], a1[mt][nt], 0, 0, 0);
  }
  // f1 = relu(D1 + bf1) -> F1s[m][n1]
#pragma unroll
  for (int mt = 0; mt < 2; mt++)
#pragma unroll
    for (int nt = 0; nt < 4; nt++) {
      int n1 = w * 64 + nt * 16 + quad * 4;
      int ml = mt * 16 + l15;
      float4 bv = *(const float4*)(bf1 + n1);
      f32x4 v = a1[mt][nt];
      short4v o = {f2bf(fmaxf(v[0] + bv.x, 0.f)), f2bf(fmaxf(v[1] + bv.y, 0.f)),
                   f2bf(fmaxf(v[2] + bv.z, 0.f)), f2bf(fmaxf(v[3] + bv.w, 0.f))};
      *(short4v*)&F1s[ml * 264 + n1] = o;
    }
  __syncthreads();

  // ---- GEMM2: C[m][n2] = f1 . W2^T ; wave owns 64 n2 ----
  const short* fb = &F1s[l15 * 264 + quad * 8];
  f32x4 a2[2][4];
#pragma unroll
  for (int i = 0; i < 2; i++)
#pragma unroll
    for (int j = 0; j < 4; j++) a2[i][j] = (f32x4){0.f, 0.f, 0.f, 0.f};
#pragma unroll
  for (int kf = 0; kf < 8; kf++) {
    bf16x8 ff[2], fw2[4];
#pragma unroll
    for (int i = 0; i < 2; i++) ff[i] = as_bf8(*(const short8*)(fb + i * 16 * 264 + kf * 32));
#pragma unroll
    for (int i = 0; i < 4; i++) fw2[i] = as_bf8(*(const short8*)(w2b + i * 4096 + kf * 32));
#pragma unroll
    for (int mt = 0; mt < 2; mt++)
#pragma unroll
      for (int nt = 0; nt < 4; nt++)
        a2[mt][nt] = __builtin_amdgcn_mfma_f32_16x16x32_bf16(ff[mt], fw2[nt], a2[mt][nt], 0, 0, 0);
  }
  // out = D2 + bf2 + xt
#pragma unroll
  for (int mt = 0; mt < 2; mt++)
#pragma unroll
    for (int nt = 0; nt < 4; nt++) {
      int n2 = w * 64 + nt * 16 + l15;
      int mg = m0 + mt * 16 + quad * 4;
      float bv = bf2[n2];
      f32x4 v = a2[mt][nt];
#pragma unroll
      for (int r = 0; r < 4; r++) {
        size_t a = (size_t)(mg + r) * D_MODEL + n2;
        out[a] = v[r] + bv + xt[a];
      }
    }
}

// ---- MFMA flash attention v13: K double-buffered LDS, V in regs, 1 barrier
// R11 analysis: wall = longest block (32 iters) x per-iter critical path
// (~4570 cyc); pipes all <40%. v13 cuts the path: (1) K LDS double-buffer ->
// stage target never aliases read target -> ONE __syncthreads per iter
// (v7 had two); (2) V direct global->reg ping-pong prefetch (v8's verified
// voff formula + swap pattern) -> V stage-writes, V LDS reads and their
// bank conflicts all gone. Grid/swizzle/Q/QK/softmax/PV math and epilogue
// are v7 verbatim. LDS 33 KB; VGPR ~120 under (256,3) cap ~170.
__global__ __launch_bounds__(256, 3) void attn_v13(const short* __restrict__ qb,
                                                   const short* __restrict__ kimg,
                                                   const short* __restrict__ vimg,
                                                   const float* __restrict__ x,
                                                   float* __restrict__ xt) {
  __shared__ __align__(16) short Ks[2 * 8192];  // two 16 KB K buffers
  __shared__ float lred[256];                   // 1 KB epilogue l-combine

  const int t = threadIdx.x, lane = t & 63, w = t >> 6;
  const int quad = lane >> 4, l15 = lane & 15, l7 = lane & 7;
  const int qa = quad & 1, q1 = quad >> 1;
  const int yy = blockIdx.y, gq = yy >> 4, rq = yy & 15;
  const int qt = gq == 0 ? 63 - rq : gq == 1 ? rq : gq == 2 ? 47 - rq : 16 + rq;
  const int bh = blockIdx.x, b = bh >> 2, h = bh & 3;
  const int ldsoff = __builtin_amdgcn_readfirstlane(w * 512);
  const short* kb_bh = kimg + (size_t)bh * 64 * 4096;
  const short* vb_bh = vimg + (size_t)bh * 64 * 4096;

  const int sb = w * 32;  // wave's key-slice base within the 128-key tile
  const int q0 = qt * 64;

  // K fragment offsets (shorts, relative to current K buffer base)
  int ka_off[2][2];
#pragma unroll
  for (int kk = 0; kk < 2; kk++)
#pragma unroll
    for (int dh = 0; dh < 2; dh++)
      ka_off[kk][dh] = (sb + kk * 16 + l15) * 64 + (((quad + 4 * dh) ^ l7) * 8);
  // V fragment offsets into a 128-key image chunk (v8 formula, verified)
  int voff[2];
#pragma unroll
  for (int kk = 0; kk < 2; kk++) {
    int sk = sb + kk * 16;
    voff[kk] = (sk >> 6) * 4096 + l15 * 64 + ((((sk & 63) >> 3) | q1) ^ l7) * 8 + qa * 4;
  }

  // Q: all 4 q-frags x 2 d-halves in registers (B-operand: n=l15, k=quad*8+j)
  bf16x8 qf[4][2];
  {
    const short* qpb = qb + ((size_t)(b * SEQ + q0 + l15)) * D_MODEL + h * HEAD_DIM + quad * 8;
#pragma unroll
    for (int qq = 0; qq < 4; qq++) {
      qf[qq][0] = as_bf8(*(const short8*)(qpb + qq * 16 * D_MODEL));
      qf[qq][1] = as_bf8(*(const short8*)(qpb + qq * 16 * D_MODEL + 32));
    }
  }

  f32x4 oacc[4][4];  // [dt][qq]: d = dt*16+quad*4+r, q = qq*16+l15 (wave-partial)
#pragma unroll
  for (int i = 0; i < 4; i++)
#pragma unroll
    for (int j = 0; j < 4; j++) oacc[i][j] = (f32x4){0.f, 0.f, 0.f, 0.f};
  float lrun[4] = {0.f, 0.f, 0.f, 0.f};

  const int niter = (qt + 2) >> 1;

  // V register ping-pong buffers (static names; swap via alternating calls)
  short4v vA[2][4], vB[2][4];

  // prologue: stage K(0) -> buf0; load V(0) regs; one drain
#pragma unroll
  for (int i = 0; i < 4; i++)
    g2lds16(kb_bh + i * 2048 + t * 8, &Ks[i * 2048 + ldsoff]);
  if (sb <= q0 + 63) {
#pragma unroll
    for (int kk = 0; kk < 2; kk++)
#pragma unroll
      for (int dt = 0; dt < 4; dt++)
        vA[kk][dt] = *(const short4v*)(vb_bh + voff[kk] + dt * 1024);
  }
  __syncthreads();

  auto body = [&](short4v(&VC)[2][4], short4v(&VN)[2][4], int it) {
    const int j0 = it * 128;
    const bool active = (j0 + sb) <= (q0 + 63);               // wave-uniform
    const bool knext = (it + 1 < niter);                      // block-uniform
    const bool vnext = knext && ((j0 + 128 + sb) <= (q0 + 63));
    const short* kb = &Ks[(it & 1) * 8192];

    uint2 pu[2][4];
    f32x4 st[2][4];
    if (active) {
      // ---- QK: A = K slice (m=key), B = Q (n=q); C rows=key, cols=q ----
#pragma unroll
      for (int kk = 0; kk < 2; kk++) {
        bf16x8 k0 = as_bf8(*(const short8*)(kb + ka_off[kk][0]));
        bf16x8 k1 = as_bf8(*(const short8*)(kb + ka_off[kk][1]));
#pragma unroll
        for (int qq = 0; qq < 4; qq++) {
          f32x4 z = (f32x4){0.f, 0.f, 0.f, 0.f};
          z = __builtin_amdgcn_mfma_f32_16x16x32_bf16(k0, qf[qq][0], z, 0, 0, 0);
          z = __builtin_amdgcn_mfma_f32_16x16x32_bf16(k1, qf[qq][1], z, 0, 0, 0);
          st[kk][qq] = z;
        }
      }
    }
    if (knext) {  // stage K(it+1) into the OTHER buffer (no read aliasing)
      const short* kc = kb_bh + (size_t)(it + 1) * 8192;
      short* kd = &Ks[((it + 1) & 1) * 8192];
#pragma unroll
      for (int i = 0; i < 4; i++)
        g2lds16(kc + i * 2048 + t * 8, kd + i * 2048 + ldsoff);
    }
    if (vnext) {  // prefetch V(it+1) regs: lands under softmax+PV+barrier
      const short* vc = vb_bh + (size_t)(it + 1) * 8192;
#pragma unroll
      for (int kk = 0; kk < 2; kk++)
#pragma unroll
        for (int dt = 0; dt < 4; dt++)
          VN[kk][dt] = *(const short4v*)(vc + voff[kk] + dt * 1024);
    }
    if (active) {
      // causal mask (sentinel -> exp2 = 0) only when slice overlaps diagonal
      if (j0 + sb + 31 > q0) {
#pragma unroll
        for (int kk = 0; kk < 2; kk++) {
          int kbase = j0 + sb + kk * 16 + quad * 4;
#pragma unroll
          for (int qq = 0; qq < 4; qq++) {
            int qrow = q0 + qq * 16 + l15;
#pragma unroll
            for (int r = 0; r < 4; r++)
              if (kbase + r > qrow) st[kk][qq][r] = -1e30f;
          }
        }
      }
      // streaming softmax: p = exp2(s) unnormalized; pack to bf16 pairs
#pragma unroll
      for (int kk = 0; kk < 2; kk++)
#pragma unroll
        for (int qq = 0; qq < 4; qq++) {
          float p0 = __builtin_amdgcn_exp2f(st[kk][qq][0]);
          float p1 = __builtin_amdgcn_exp2f(st[kk][qq][1]);
          float p2 = __builtin_amdgcn_exp2f(st[kk][qq][2]);
          float p3 = __builtin_amdgcn_exp2f(st[kk][qq][3]);
          lrun[qq] += p0 + p1 + p2 + p3;
          pu[kk][qq].x = (__float_as_uint(p0) >> 16) | (__float_as_uint(p1) & 0xffff0000u);
          pu[kk][qq].y = (__float_as_uint(p2) >> 16) | (__float_as_uint(p3) & 0xffff0000u);
        }
      // ---- PV: A = V^T regs (m=d, k=key), B = P regs (n=q, k=quad*4+j) ----
#pragma unroll
      for (int kk = 0; kk < 2; kk++) {
        union { uint2 u; short4v s; } pb0, pb1, pb2, pb3;
        pb0.u = pu[kk][0];
        pb1.u = pu[kk][1];
        pb2.u = pu[kk][2];
        pb3.u = pu[kk][3];
#pragma unroll
        for (int dt = 0; dt < 4; dt++) {
          short4v vv = VC[kk][dt];
          oacc[dt][0] = mfma16bf(vv, pb0.s, oacc[dt][0]);
          oacc[dt][1] = mfma16bf(vv, pb1.s, oacc[dt][1]);
          oacc[dt][2] = mfma16bf(vv, pb2.s, oacc[dt][2]);
          oacc[dt][3] = mfma16bf(vv, pb3.s, oacc[dt][3]);
        }
      }
    }
    // single per-iter barrier: all waves past their K(it) reads, and the
    // implicit vmcnt(0) drain completes K(it+1) before next iter reads it.
    __syncthreads();
  };

  int it = 0;
  while (it < niter) {
    body(vA, vB, it);
    if (++it >= niter) break;
    body(vB, vA, it);
    ++it;
  }

  // ---- epilogue (v7 verbatim): combine wave-partials by pure addition ----
#pragma unroll
  for (int qq = 0; qq < 4; qq++) {
    lrun[qq] += __shfl_xor(lrun[qq], 16);
    lrun[qq] += __shfl_xor(lrun[qq], 32);
  }
  float* ored = (float*)Ks;  // 4 regions x 1024 f32 = 16 KB (first K buffer)
  __syncthreads();           // loop LDS use fully complete
  if (quad == 0) {
#pragma unroll
    for (int qq = 0; qq < 4; qq++) lred[(w * 4 + qq) * 16 + l15] = lrun[qq];
  }
  // 3 rotation rounds; wave w accumulates region w into its own tile dt==w.
#pragma unroll
  for (int rr = 1; rr < 4; rr++) {
#pragma unroll
    for (int dt = 0; dt < 4; dt++)
      if (dt == ((w + rr) & 3)) {
#pragma unroll
        for (int qq = 0; qq < 4; qq++)
#pragma unroll
          for (int e = 0; e < 4; e++)
            ored[dt * 1024 + (quad * 4 + e) * 64 + qq * 16 + l15] = oacc[dt][qq][e];
      }
    __syncthreads();
#pragma unroll
    for (int dt = 0; dt < 4; dt++)
      if (dt == w) {
#pragma unroll
        for (int qq = 0; qq < 4; qq++)
#pragma unroll
          for (int e = 0; e < 4; e++)
            oacc[dt][qq][e] += ored[dt * 1024 + (quad * 4 + e) * 64 + qq * 16 + l15];
      }
    if (rr < 3) __syncthreads();
  }
  // l totals and final write: wave w owns d-range [w*16, w*16+16)
  float inv[4];
#pragma unroll
  for (int qq = 0; qq < 4; qq++) {
    float s = lred[qq * 16 + l15] + lred[(4 + qq) * 16 + l15] +
              lred[(8 + qq) * 16 + l15] + lred[(12 + qq) * 16 + l15];
    inv[qq] = 1.0f / s;
  }
#pragma unroll
  for (int dt = 0; dt < 4; dt++)
    if (dt == w) {
      size_t rowb = ((size_t)(b * SEQ + q0 + l15)) * D_MODEL + h * HEAD_DIM + dt * 16 + quad * 4;
#pragma unroll
      for (int qq = 0; qq < 4; qq++) {
        size_t a = rowb + (size_t)qq * 16 * D_MODEL;
        float4 xv = *(const float4*)(x + a);
        float4 o = make_float4(oacc[dt][qq][0] * inv[qq] + xv.x,
                               oacc[dt][qq][1] * inv[qq] + xv.y,
                               oacc[dt][qq][2] * inv[qq] + xv.z,
                               oacc[dt][qq][3] * inv[qq] + xv.w);
        *(float4*)(xt + a) = o;
      }
    }
}

// ---------------------------------------------------------------------------
extern "C" void kernel_launch(void* const* d_in, const int* in_sizes, int n_in,
                              void* d_out, int out_size, void* d_ws,
                              size_t ws_size, hipStream_t stream) {
  const float* x = (const float*)d_in[0];
  const float* Wq = (const float*)d_in[1];
  const float* Wk = (const float*)d_in[2];
  const float* Wv = (const float*)d_in[3];
  const float* g1 = (const float*)d_in[4];
  const float* b1 = (const float*)d_in[5];
  const float* g2 = (const float*)d_in[6];
  const float* b2 = (const float*)d_in[7];
  const float* W1 = (const float*)d_in[8];
  const float* bf1 = (const float*)d_in[9];
  const float* W2 = (const float*)d_in[10];
  const float* bf2 = (const float*)d_in[11];
  float* out = (float*)d_out;

  char* ws = (char*)d_ws;
  float* xt = (float*)ws;                       // 16 MB
  short* q_bf = (short*)(ws + (16u << 20));     // 8 MB
  short* kimg = (short*)(ws + (24u << 20));     // 8 MB
  short* vimg = (short*)(ws + (32u << 20));     // 8 MB
  short* wq_i = (short*)(ws + (48u << 20));     // 5 x 128 KB swizzled weights
  short* wk_i = wq_i + 65536;
  short* wv_i = wq_i + 2 * 65536;
  short* w1_i = wq_i + 3 * 65536;
  short* w2_i = wq_i + 4 * 65536;

  dim3 blk(256);
  wcvt<<<160, blk, 0, stream>>>(Wq, Wk, Wv, W1, W2, wq_i, wk_i, wv_i, w1_i, w2_i);
  qkv_ln<<<dim3(MROWS / 64, 3), blk, 0, stream>>>(wq_i, wk_i, wv_i, x, g1, b1,
                                                  q_bf, kimg, vimg);
  attn_v13<<<dim3(16, 64), blk, 0, stream>>>(q_bf, kimg, vimg, x, xt);
  ffn_ln<<<MROWS / 32, blk, 0, stream>>>(w1_i, w2_i, g2, b2, bf1, bf2, xt, out);
}

// Round 13
// 169.941 us; speedup vs baseline: 1.6110x; 1.6110x over previous
//
#include <hip/hip_runtime.h>
#include <math.h>

#define D_MODEL 256
#define NHEAD 4
#define HEAD_DIM 64
#define SEQ 4096
#define BATCH 4
#define MROWS (BATCH * SEQ)

typedef __attribute__((ext_vector_type(8))) short short8;
typedef __attribute__((ext_vector_type(4))) short short4v;
typedef __attribute__((ext_vector_type(8))) __bf16 bf16x8;
typedef __attribute__((ext_vector_type(4))) float f32x4;

__device__ inline short f2bf(float f) {  // RNE fp32->bf16
  unsigned u = __float_as_uint(f);
  u += 0x7fffu + ((u >> 16) & 1u);
  return (short)(u >> 16);
}
__device__ inline bf16x8 as_bf8(short8 s) {
  union { short8 s; bf16x8 b; } u;
  u.s = s;
  return u.b;
}
// async global->LDS, 16B per lane; LDS dest = wave-uniform base + lane*16
__device__ __forceinline__ void g2lds16(const void* g, void* l) {
  __builtin_amdgcn_global_load_lds(
      (const __attribute__((address_space(1))) unsigned int*)g,
      (__attribute__((address_space(3))) unsigned int*)l, 16, 0, 0);
}

// 16x16x16 bf16 MFMA: B-operand k-map (quad*4+j) == QK C-layout k-map,
// so P feeds PV straight from registers (no LDS round-trip).
__device__ __forceinline__ f32x4 mfma16bf(short4v a, short4v b, f32x4 c) {
#if __has_builtin(__builtin_amdgcn_mfma_f32_16x16x16bf16_1k)
  return __builtin_amdgcn_mfma_f32_16x16x16bf16_1k(a, b, c, 0, 0, 0);
#else
  asm("v_mfma_f32_16x16x16_bf16 %0, %1, %2, %0" : "+v"(c) : "v"(a), "v"(b));
  return c;
#endif
}

#define QSCALE 0.1803368801111204f  /* 0.125 * log2(e): exp2-domain scores */

// ---- weight cvt fp32->bf16, row-major with XOR-swizzled 16B groups --------
// element (n,k) -> n*256 + (k>>5)*32 + (((k>>3)&3) ^ (n&3))*8 + (k&7)
__global__ __launch_bounds__(256) void wcvt(const float* __restrict__ s0, const float* __restrict__ s1,
                                            const float* __restrict__ s2, const float* __restrict__ s3,
                                            const float* __restrict__ s4, short* __restrict__ d0,
                                            short* __restrict__ d1, short* __restrict__ d2,
                                            short* __restrict__ d3, short* __restrict__ d4) {
  int mat = blockIdx.x >> 5;
  int e = ((blockIdx.x & 31) * 256 + threadIdx.x) * 8;
  const float* s = mat == 0 ? s0 : mat == 1 ? s1 : mat == 2 ? s2 : mat == 3 ? s3 : s4;
  short* d = mat == 0 ? d0 : mat == 1 ? d1 : mat == 2 ? d2 : mat == 3 ? d3 : d4;
  int n = e >> 8, k0 = e & 255;
  float4 f0 = *(const float4*)(s + n * 256 + k0);
  float4 f1 = *(const float4*)(s + n * 256 + k0 + 4);
  short8 o = {f2bf(f0.x), f2bf(f0.y), f2bf(f0.z), f2bf(f0.w),
              f2bf(f1.x), f2bf(f1.y), f2bf(f1.z), f2bf(f1.w)};
  int chunk = k0 >> 5, g = (k0 >> 3) & 3;
  *(short8*)(d + n * 256 + chunk * 32 + ((g ^ (n & 3)) * 8)) = o;
}

// ---- QKV GEMM with fused LayerNorm1 (verified R10: best-total config) -----
// LN computed in-kernel (ffn_ln's verified LN block, 8 passes for 64 rows),
// written straight into Xs with the same swizzle ln_sw used.
__global__ __launch_bounds__(256) void qkv_ln(
    const short* __restrict__ Wqi, const short* __restrict__ Wki,
    const short* __restrict__ Wvi, const float* __restrict__ x,
    const float* __restrict__ g1v, const float* __restrict__ b1v,
    short* __restrict__ qo, short* __restrict__ kimg, short* __restrict__ vimg) {
  __shared__ __align__(16) short Xs[64 * 256];  // 32 KB
  const int t = threadIdx.x, lane = t & 63, w = t >> 6;
  const int l15 = lane & 15, quad = lane >> 4;
  const int m0 = blockIdx.x * 64;
  const int which = blockIdx.y;
  const short* Wb = which == 0 ? Wqi : which == 1 ? Wki : Wvi;

  // ---- fused LN1: 8 rows per pass (32 thr/row), 8 passes -> Xs swizzled ----
  {
    const int r = t >> 5, c8 = t & 31;
    float4 ga = *(const float4*)(g1v + c8 * 8);
    float4 gc = *(const float4*)(g1v + c8 * 8 + 4);
    float4 ba = *(const float4*)(b1v + c8 * 8);
    float4 bc = *(const float4*)(b1v + c8 * 8 + 4);
#pragma unroll
    for (int pass = 0; pass < 8; pass++) {
      int row = pass * 8 + r;
      const float* xr = x + (size_t)(m0 + row) * D_MODEL + c8 * 8;
      float4 a = *(const float4*)xr;
      float4 c = *(const float4*)(xr + 4);
      float s = a.x + a.y + a.z + a.w + c.x + c.y + c.z + c.w;
#pragma unroll
      for (int off = 16; off > 0; off >>= 1) s += __shfl_xor(s, off);
      float mu = s * (1.0f / D_MODEL);
      float d0 = a.x - mu, d1 = a.y - mu, d2 = a.z - mu, d3 = a.w - mu;
      float d4 = c.x - mu, d5 = c.y - mu, d6 = c.z - mu, d7 = c.w - mu;
      float ss = d0 * d0 + d1 * d1 + d2 * d2 + d3 * d3 + d4 * d4 + d5 * d5 + d6 * d6 + d7 * d7;
#pragma unroll
      for (int off = 16; off > 0; off >>= 1) ss += __shfl_xor(ss, off);
      float rstd = rsqrtf(ss * (1.0f / D_MODEL) + 1e-5f);
      short8 ov = {f2bf(d0 * rstd * ga.x + ba.x), f2bf(d1 * rstd * ga.y + ba.y),
                   f2bf(d2 * rstd * ga.z + ba.z), f2bf(d3 * rstd * ga.w + ba.w),
                   f2bf(d4 * rstd * gc.x + bc.x), f2bf(d5 * rstd * gc.y + bc.y),
                   f2bf(d6 * rstd * gc.z + bc.z), f2bf(d7 * rstd * gc.w + bc.w)};
      int chunk = c8 >> 2, gr = c8 & 3;
      *(short8*)&Xs[row * 256 + chunk * 32 + ((gr ^ (row & 3)) * 8)] = ov;
    }
  }
  __syncthreads();

  // hoisted fragment bases (all further offsets compile-time)
  const short* xb = &Xs[l15 * 256 + ((quad ^ (l15 & 3)) * 8)];
  const short* wb = Wb + (size_t)(w * 64 + l15) * 256 + ((quad ^ (l15 & 3)) * 8);

  f32x4 acc[4][4];
#pragma unroll
  for (int i = 0; i < 4; i++)
#pragma unroll
    for (int j = 0; j < 4; j++) acc[i][j] = (f32x4){0.f, 0.f, 0.f, 0.f};

#pragma unroll
  for (int kf = 0; kf < 8; kf++) {
    bf16x8 fx[4], fw[4];
#pragma unroll
    for (int i = 0; i < 4; i++) {
      fx[i] = as_bf8(*(const short8*)(xb + i * 4096 + kf * 32));
      fw[i] = as_bf8(*(const short8*)(wb + i * 4096 + kf * 32));
    }
    if (which == 2) {
#pragma unroll
      for (int mt = 0; mt < 4; mt++)
#pragma unroll
        for (int nt = 0; nt < 4; nt++)
          acc[mt][nt] = __builtin_amdgcn_mfma_f32_16x16x32_bf16(fx[mt], fw[nt], acc[mt][nt], 0, 0, 0);
    } else {
#pragma unroll
      for (int mt = 0; mt < 4; mt++)
#pragma unroll
        for (int nt = 0; nt < 4; nt++)
          acc[mt][nt] = __builtin_amdgcn_mfma_f32_16x16x32_bf16(fw[nt], fx[mt], acc[mt][nt], 0, 0, 0);
    }
  }

#pragma unroll
  for (int mt = 0; mt < 4; mt++)
#pragma unroll
    for (int nt = 0; nt < 4; nt++) {
      f32x4 v = acc[mt][nt];
      if (which == 2) {  // VT image: C[m=s][n=feature] (rows via quad*4+r)
        int n = w * 64 + nt * 16 + l15;
        int mr = m0 + mt * 16 + quad * 4;
        int b = mr >> 12, s = mr & 4095, h = n >> 6, d = n & 63;
        size_t off = ((size_t)(b * NHEAD + h) * 64 + (s >> 6)) * 4096 +
                     (size_t)d * 64 + ((((s & 63) >> 3) ^ (d & 7)) * 8) + (s & 7);
        short4v o = {f2bf(v[0]), f2bf(v[1]), f2bf(v[2]), f2bf(v[3])};
        *(short4v*)(vimg + off) = o;
      } else {  // C[n][m]: col = m via l15, row = n via quad*4+r
        int m = m0 + mt * 16 + l15;
        int nb = w * 64 + nt * 16 + quad * 4;
        if (which == 0) {  // Q row-major, exp2-domain scale folded in
          v *= QSCALE;
          short4v o = {f2bf(v[0]), f2bf(v[1]), f2bf(v[2]), f2bf(v[3])};
          *(short4v*)(qo + (size_t)m * D_MODEL + nb) = o;
        } else {  // K image
          int b = m >> 12, s = m & 4095, h = nb >> 6, d = nb & 63;
          size_t off = ((size_t)(b * NHEAD + h) * 64 + (s >> 6)) * 4096 +
                       (size_t)(s & 63) * 64 + (((d >> 3) ^ (s & 7)) * 8) + (d & 7);
          short4v o = {f2bf(v[0]), f2bf(v[1]), f2bf(v[2]), f2bf(v[3])};
          *(short4v*)(kimg + off) = o;
        }
      }
    }
}

// ---- FFN with fused LayerNorm2: reads xt, LN in-kernel -> Hs, 2 GEMMs -----
// (verified passing R4-R11). Single block per row-tile -> LN amortizes.
__global__ __launch_bounds__(256) void ffn_ln(
    const short* __restrict__ w1i, const short* __restrict__ w2i,
    const float* __restrict__ g2v, const float* __restrict__ b2v,
    const float* __restrict__ bf1, const float* __restrict__ bf2,
    const float* __restrict__ xt, float* __restrict__ out) {
  __shared__ __align__(16) short Hs[32 * 256];   // 16 KB (image layout)
  __shared__ __align__(16) short F1s[32 * 264];  // 16.5 KB (padded rows)
  const int t = threadIdx.x, lane = t & 63, w = t >> 6;
  const int l15 = lane & 15, quad = lane >> 4;
  const int m0 = blockIdx.x * 32;

  // ---- fused LN2: 8 rows per pass (32 thr/row), 4 passes -> Hs swizzled ----
  {
    const int r = t >> 5, c8 = t & 31;
    float4 ga = *(const float4*)(g2v + c8 * 8);
    float4 gc = *(const float4*)(g2v + c8 * 8 + 4);
    float4 ba = *(const float4*)(b2v + c8 * 8);
    float4 bc = *(const float4*)(b2v + c8 * 8 + 4);
#pragma unroll
    for (int pass = 0; pass < 4; pass++) {
      int row = pass * 8 + r;
      const float* xr = xt + (size_t)(m0 + row) * D_MODEL + c8 * 8;
      float4 a = *(const float4*)xr;
      float4 c = *(const float4*)(xr + 4);
      float s = a.x + a.y + a.z + a.w + c.x + c.y + c.z + c.w;
#pragma unroll
      for (int off = 16; off > 0; off >>= 1) s += __shfl_xor(s, off);
      float mu = s * (1.0f / D_MODEL);
      float d0 = a.x - mu, d1 = a.y - mu, d2 = a.z - mu, d3 = a.w - mu;
      float d4 = c.x - mu, d5 = c.y - mu, d6 = c.z - mu, d7 = c.w - mu;
      float ss = d0 * d0 + d1 * d1 + d2 * d2 + d3 * d3 + d4 * d4 + d5 * d5 + d6 * d6 + d7 * d7;
#pragma unroll
      for (int off = 16; off > 0; off >>= 1) ss += __shfl_xor(ss, off);
      float rstd = rsqrtf(ss * (1.0f / D_MODEL) + 1e-5f);
      short8 ov = {f2bf(d0 * rstd * ga.x + ba.x), f2bf(d1 * rstd * ga.y + ba.y),
                   f2bf(d2 * rstd * ga.z + ba.z), f2bf(d3 * rstd * ga.w + ba.w),
                   f2bf(d4 * rstd * gc.x + bc.x), f2bf(d5 * rstd * gc.y + bc.y),
                   f2bf(d6 * rstd * gc.z + bc.z), f2bf(d7 * rstd * gc.w + bc.w)};
      int chunk = c8 >> 2, gr = c8 & 3;
      *(short8*)&Hs[row * 256 + chunk * 32 + ((gr ^ (row & 3)) * 8)] = ov;
    }
  }
  __syncthreads();

  const short* hb = &Hs[l15 * 256 + ((quad ^ (l15 & 3)) * 8)];
  const short* w1b = w1i + (size_t)(w * 64 + l15) * 256 + ((quad ^ (l15 & 3)) * 8);
  const short* w2b = w2i + (size_t)(w * 64 + l15) * 256 + ((quad ^ (l15 & 3)) * 8);

  // ---- GEMM1: C[n1][m] = W1 . h^T ; wave owns 64 n1, all 32 m ----
  f32x4 a1[2][4];
#pragma unroll
  for (int i = 0; i < 2; i++)
#pragma unroll
    for (int j = 0; j < 4; j++) a1[i][j] = (f32x4){0.f, 0.f, 0.f, 0.f};
#pragma unroll
  for (int kf = 0; kf < 8; kf++) {
    bf16x8 fh[2], fw1[4];
#pragma unroll
    for (int i = 0; i < 2; i++) fh[i] = as_bf8(*(const short8*)(hb + i * 4096 + kf * 32));
#pragma unroll
    for (int i = 0; i < 4; i++) fw1[i] = as_bf8(*(const short8*)(w1b + i * 4096 + kf * 32));
#pragma unroll
    for (int mt = 0; mt < 2; mt++)
#pragma unroll
      for (int nt = 0; nt < 4; nt++)
        a1[mt][nt] = __builtin_amdgcn_mfma_f32_16x16x32_bf16(fw1[nt], fh[mt], a1[mt][nt], 0, 0, 0);
  }
  // f1 = relu(D1 + bf1) -> F1s[m][n1]
#pragma unroll
  for (int mt = 0; mt < 2; mt++)
#pragma unroll
    for (int nt = 0; nt < 4; nt++) {
      int n1 = w * 64 + nt * 16 + quad * 4;
      int ml = mt * 16 + l15;
      float4 bv = *(const float4*)(bf1 + n1);
      f32x4 v = a1[mt][nt];
      short4v o = {f2bf(fmaxf(v[0] + bv.x, 0.f)), f2bf(fmaxf(v[1] + bv.y, 0.f)),
                   f2bf(fmaxf(v[2] + bv.z, 0.f)), f2bf(fmaxf(v[3] + bv.w, 0.f))};
      *(short4v*)&F1s[ml * 264 + n1] = o;
    }
  __syncthreads();

  // ---- GEMM2: C[m][n2] = f1 . W2^T ; wave owns 64 n2 ----
  const short* fb = &F1s[l15 * 264 + quad * 8];
  f32x4 a2[2][4];
#pragma unroll
  for (int i = 0; i < 2; i++)
#pragma unroll
    for (int j = 0; j < 4; j++) a2[i][j] = (f32x4){0.f, 0.f, 0.f, 0.f};
#pragma unroll
  for (int kf = 0; kf < 8; kf++) {
    bf16x8 ff[2], fw2[4];
#pragma unroll
    for (int i = 0; i < 2; i++) ff[i] = as_bf8(*(const short8*)(fb + i * 16 * 264 + kf * 32));
#pragma unroll
    for (int i = 0; i < 4; i++) fw2[i] = as_bf8(*(const short8*)(w2b + i * 4096 + kf * 32));
#pragma unroll
    for (int mt = 0; mt < 2; mt++)
#pragma unroll
      for (int nt = 0; nt < 4; nt++)
        a2[mt][nt] = __builtin_amdgcn_mfma_f32_16x16x32_bf16(ff[mt], fw2[nt], a2[mt][nt], 0, 0, 0);
  }
  // out = D2 + bf2 + xt
#pragma unroll
  for (int mt = 0; mt < 2; mt++)
#pragma unroll
    for (int nt = 0; nt < 4; nt++) {
      int n2 = w * 64 + nt * 16 + l15;
      int mg = m0 + mt * 16 + quad * 4;
      float bv = bf2[n2];
      f32x4 v = a2[mt][nt];
#pragma unroll
      for (int r = 0; r < 4; r++) {
        size_t a = (size_t)(mg + r) * D_MODEL + n2;
        out[a] = v[r] + bv + xt[a];
      }
    }
}

// ---- MFMA flash attention v7 (VERBATIM: passed R3/R10/R11 at 61-62 us) ----
// Keys split across waves; LDS-staged 2-phase pipeline; P in registers;
// epilogue combine via pure addition. grid (16 bh, 64 y) with balanced
// y->qt swizzle. All register/reg-double-buffer successors (v8-v13) lost
// to spills or packing; this is the verified best.
__global__ __launch_bounds__(256, 3) void attn_v7(const short* __restrict__ qb,
                                                  const short* __restrict__ kimg,
                                                  const short* __restrict__ vimg,
                                                  const float* __restrict__ x,
                                                  float* __restrict__ xt) {
  __shared__ __align__(16) short Ks[2 * 4096];
  __shared__ __align__(16) short Vs[2 * 4096];

  const int t = threadIdx.x, lane = t & 63, w = t >> 6;
  const int quad = lane >> 4, l15 = lane & 15, l7 = lane & 7;
  const int qa = quad & 1, q1 = quad >> 1;
  const int yy = blockIdx.y, gq = yy >> 4, rq = yy & 15;
  const int qt = gq == 0 ? 63 - rq : gq == 1 ? rq : gq == 2 ? 47 - rq : 16 + rq;
  const int bh = blockIdx.x, b = bh >> 2, h = bh & 3;
  const int ldsoff = __builtin_amdgcn_readfirstlane(w * 512);
  const short* kb_bh = kimg + (size_t)bh * 64 * 4096;
  const short* vb_bh = vimg + (size_t)bh * 64 * 4096;

  const int sb = w * 32;  // wave's key-slice base within the 128-key tile
  const int q0 = qt * 64;

  // K fragment bases: rows sb+kk*16+l15 (row&7 == l7), granule (quad+4*dh)^l7
  const short* ka[2][2];
#pragma unroll
  for (int kk = 0; kk < 2; kk++)
#pragma unroll
    for (int dh = 0; dh < 2; dh++)
      ka[kk][dh] = &Ks[(sb + kk * 16 + l15) * 64 + (((quad + 4 * dh) ^ l7) * 8)];
  // V fragment bases (V^T image): row d = dt*16+l15, keys sb+kk*16+quad*4..+3
  const short* va[2];
#pragma unroll
  for (int kk = 0; kk < 2; kk++) {
    int sk = sb + kk * 16;
    va[kk] = &Vs[(sk >> 6) * 4096 + l15 * 64 + ((((((sk & 63) >> 3) | q1) ^ l7)) * 8) + qa * 4];
  }

  // Q: all 4 q-frags x 2 d-halves in registers (B-operand: n=l15, k=quad*8+j)
  bf16x8 qf[4][2];
  {
    const short* qpb = qb + ((size_t)(b * SEQ + q0 + l15)) * D_MODEL + h * HEAD_DIM + quad * 8;
#pragma unroll
    for (int qq = 0; qq < 4; qq++) {
      qf[qq][0] = as_bf8(*(const short8*)(qpb + qq * 16 * D_MODEL));
      qf[qq][1] = as_bf8(*(const short8*)(qpb + qq * 16 * D_MODEL + 32));
    }
  }

  f32x4 oacc[4][4];  // [dt][qq]: d = dt*16+quad*4+r, q = qq*16+l15 (wave-partial)
#pragma unroll
  for (int i = 0; i < 4; i++)
#pragma unroll
    for (int j = 0; j < 4; j++) oacc[i][j] = (f32x4){0.f, 0.f, 0.f, 0.f};
  float lrun[4] = {0.f, 0.f, 0.f, 0.f};  // per-qq partial row sums

  const int niter = (qt + 2) >> 1;

  // prologue: stage K(0) and V(0); single full drain
#pragma unroll
  for (int i = 0; i < 4; i++) {
    g2lds16(kb_bh + i * 2048 + t * 8, &Ks[i * 2048 + ldsoff]);
    g2lds16(vb_bh + i * 2048 + t * 8, &Vs[i * 2048 + ldsoff]);
  }
  __syncthreads();

  for (int it = 0; it < niter; it++) {
    const int j0 = it * 128;
    // wave active iff its smallest key <= largest q row of the tile
    const bool active = (j0 + sb) <= (q0 + 63);

    uint2 pu[2][4];
    if (active) {
      // ---- QK: A = K slice (m=key), B = Q (n=q); C rows=key, cols=q ----
      f32x4 st[2][4];
#pragma unroll
      for (int kk = 0; kk < 2; kk++) {
        bf16x8 k0 = as_bf8(*(const short8*)(ka[kk][0]));
        bf16x8 k1 = as_bf8(*(const short8*)(ka[kk][1]));
#pragma unroll
        for (int qq = 0; qq < 4; qq++) {
          f32x4 z = (f32x4){0.f, 0.f, 0.f, 0.f};
          z = __builtin_amdgcn_mfma_f32_16x16x32_bf16(k0, qf[qq][0], z, 0, 0, 0);
          z = __builtin_amdgcn_mfma_f32_16x16x32_bf16(k1, qf[qq][1], z, 0, 0, 0);
          st[kk][qq] = z;
        }
      }
      // causal mask (sentinel -> exp2 = 0) only when slice overlaps diagonal
      if (j0 + sb + 31 > q0) {
#pragma unroll
        for (int kk = 0; kk < 2; kk++) {
          int kbase = j0 + sb + kk * 16 + quad * 4;
#pragma unroll
          for (int qq = 0; qq < 4; qq++) {
            int qrow = q0 + qq * 16 + l15;
#pragma unroll
            for (int r = 0; r < 4; r++)
              if (kbase + r > qrow) st[kk][qq][r] = -1e30f;
          }
        }
      }
      // streaming softmax: p = exp2(s) unnormalized; pack to bf16 pairs
#pragma unroll
      for (int kk = 0; kk < 2; kk++)
#pragma unroll
        for (int qq = 0; qq < 4; qq++) {
          float p0 = __builtin_amdgcn_exp2f(st[kk][qq][0]);
          float p1 = __builtin_amdgcn_exp2f(st[kk][qq][1]);
          float p2 = __builtin_amdgcn_exp2f(st[kk][qq][2]);
          float p3 = __builtin_amdgcn_exp2f(st[kk][qq][3]);
          lrun[qq] += p0 + p1 + p2 + p3;
          pu[kk][qq].x = (__float_as_uint(p0) >> 16) | (__float_as_uint(p1) & 0xffff0000u);
          pu[kk][qq].y = (__float_as_uint(p2) >> 16) | (__float_as_uint(p3) & 0xffff0000u);
        }
    }

    // mid barrier: drains V(it) stage; all waves done reading Ks
    __syncthreads();

    if (it + 1 < niter) {  // stage K(it+1): flies under the PV phase below
      const short* kc_base = kb_bh + (size_t)(2 * (it + 1)) * 4096;
#pragma unroll
      for (int i = 0; i < 4; i++)
        g2lds16(kc_base + i * 2048 + t * 8, &Ks[i * 2048 + ldsoff]);
    }

    // ---- PV: A = V^T slice (m=d, k=key), B = P regs (n=q, k=quad*4+j) ----
    if (active) {
#pragma unroll
      for (int kk = 0; kk < 2; kk++) {
        union { uint2 u; short4v s; } pb0, pb1, pb2, pb3;
        pb0.u = pu[kk][0];
        pb1.u = pu[kk][1];
        pb2.u = pu[kk][2];
        pb3.u = pu[kk][3];
#pragma unroll
        for (int dt = 0; dt < 4; dt++) {
          short4v vv = *(const short4v*)(va[kk] + dt * 1024);
          oacc[dt][0] = mfma16bf(vv, pb0.s, oacc[dt][0]);
          oacc[dt][1] = mfma16bf(vv, pb1.s, oacc[dt][1]);
          oacc[dt][2] = mfma16bf(vv, pb2.s, oacc[dt][2]);
          oacc[dt][3] = mfma16bf(vv, pb3.s, oacc[dt][3]);
        }
      }
    }

    // end barrier: drains K(it+1) stage; all waves done reading Vs
    __syncthreads();

    if (it + 1 < niter) {
      const short* vc_base = vb_bh + (size_t)(2 * (it + 1)) * 4096;
#pragma unroll
      for (int i = 0; i < 4; i++)
        g2lds16(vc_base + i * 2048 + t * 8, &Vs[i * 2048 + ldsoff]);
    }
  }

  // ---- epilogue: combine wave-partials (pure addition; no max used) ----
  // quad-reduce lrun: lane's lrun[qq] covers keys (kk,quad,r) of this wave
#pragma unroll
  for (int qq = 0; qq < 4; qq++) {
    lrun[qq] += __shfl_xor(lrun[qq], 16);
    lrun[qq] += __shfl_xor(lrun[qq], 32);
  }
  float* ored = (float*)Ks;  // 4 regions x 1024 f32 = 16 KB
  float* lred = (float*)Vs;  // 4 waves x 4 qq x 16 = 256 f32
  __syncthreads();           // loop LDS use fully complete
  if (quad == 0) {
#pragma unroll
    for (int qq = 0; qq < 4; qq++) lred[(w * 4 + qq) * 16 + l15] = lrun[qq];
  }
  // 3 rotation rounds; wave w accumulates region w into its own tile dt==w.
  // All tile indices static (rule #20); predicates are wave-uniform.
#pragma unroll
  for (int rr = 1; rr < 4; rr++) {
#pragma unroll
    for (int dt = 0; dt < 4; dt++)
      if (dt == ((w + rr) & 3)) {
#pragma unroll
        for (int qq = 0; qq < 4; qq++)
#pragma unroll
          for (int e = 0; e < 4; e++)
            ored[dt * 1024 + (quad * 4 + e) * 64 + qq * 16 + l15] = oacc[dt][qq][e];
      }
    __syncthreads();
#pragma unroll
    for (int dt = 0; dt < 4; dt++)
      if (dt == w) {
#pragma unroll
        for (int qq = 0; qq < 4; qq++)
#pragma unroll
          for (int e = 0; e < 4; e++)
            oacc[dt][qq][e] += ored[dt * 1024 + (quad * 4 + e) * 64 + qq * 16 + l15];
      }
    if (rr < 3) __syncthreads();
  }
  // l totals and final write: wave w owns d-range [w*16, w*16+16)
  float inv[4];
#pragma unroll
  for (int qq = 0; qq < 4; qq++) {
    float s = lred[qq * 16 + l15] + lred[(4 + qq) * 16 + l15] +
              lred[(8 + qq) * 16 + l15] + lred[(12 + qq) * 16 + l15];
    inv[qq] = 1.0f / s;
  }
#pragma unroll
  for (int dt = 0; dt < 4; dt++)
    if (dt == w) {
      size_t rowb = ((size_t)(b * SEQ + q0 + l15)) * D_MODEL + h * HEAD_DIM + dt * 16 + quad * 4;
#pragma unroll
      for (int qq = 0; qq < 4; qq++) {
        size_t a = rowb + (size_t)qq * 16 * D_MODEL;
        float4 xv = *(const float4*)(x + a);
        float4 o = make_float4(oacc[dt][qq][0] * inv[qq] + xv.x,
                               oacc[dt][qq][1] * inv[qq] + xv.y,
                               oacc[dt][qq][2] * inv[qq] + xv.z,
                               oacc[dt][qq][3] * inv[qq] + xv.w);
        *(float4*)(xt + a) = o;
      }
    }
}

// ---------------------------------------------------------------------------
extern "C" void kernel_launch(void* const* d_in, const int* in_sizes, int n_in,
                              void* d_out, int out_size, void* d_ws,
                              size_t ws_size, hipStream_t stream) {
  const float* x = (const float*)d_in[0];
  const float* Wq = (const float*)d_in[1];
  const float* Wk = (const float*)d_in[2];
  const float* Wv = (const float*)d_in[3];
  const float* g1 = (const float*)d_in[4];
  const float* b1 = (const float*)d_in[5];
  const float* g2 = (const float*)d_in[6];
  const float* b2 = (const float*)d_in[7];
  const float* W1 = (const float*)d_in[8];
  const float* bf1 = (const float*)d_in[9];
  const float* W2 = (const float*)d_in[10];
  const float* bf2 = (const float*)d_in[11];
  float* out = (float*)d_out;

  char* ws = (char*)d_ws;
  float* xt = (float*)ws;                       // 16 MB
  short* q_bf = (short*)(ws + (16u << 20));     // 8 MB
  short* kimg = (short*)(ws + (24u << 20));     // 8 MB
  short* vimg = (short*)(ws + (32u << 20));     // 8 MB
  short* wq_i = (short*)(ws + (48u << 20));     // 5 x 128 KB swizzled weights
  short* wk_i = wq_i + 65536;
  short* wv_i = wq_i + 2 * 65536;
  short* w1_i = wq_i + 3 * 65536;
  short* w2_i = wq_i + 4 * 65536;

  dim3 blk(256);
  wcvt<<<160, blk, 0, stream>>>(Wq, Wk, Wv, W1, W2, wq_i, wk_i, wv_i, w1_i, w2_i);
  qkv_ln<<<dim3(MROWS / 64, 3), blk, 0, stream>>>(wq_i, wk_i, wv_i, x, g1, b1,
                                                  q_bf, kimg, vimg);
  attn_v7<<<dim3(16, 64), blk, 0, stream>>>(q_bf, kimg, vimg, x, xt);
  ffn_ln<<<MROWS / 32, blk, 0, stream>>>(w1_i, w2_i, g2, b2, bf1, bf2, xt, out);
}